// Round 15
// baseline (792.245 us; speedup 1.0000x reference)
//
#include <hip/hip_runtime.h>
#include <stdint.h>

// Problem constants
#define N_ROWS 16384   // 16*1024 flattened input rows
#define N_EMB  8192    // codebook size
#define C_DIM  256     // embedding dim
#define NKT    8       // pure-bf16 GEMM: K=256, 8 K-tiles of 32 (R9-validated)

// d_out layout (float element offsets), outputs concatenated in return order:
// loss(1), quantized_st(16*1024*3*256), perplexity(1), encoding_indices(16384*3), distances(16384*8192)
#define OFF_LOSS 0ull
#define OFF_Q    1ull
#define OFF_PERP 12582913ull
#define OFF_IDX  12582914ull
#define OFF_DIST 12632066ull

typedef short bf16x8 __attribute__((ext_vector_type(8)));
typedef float f32x4  __attribute__((ext_vector_type(4)));
typedef float f32x2  __attribute__((ext_vector_type(2)));

#define LT(av,ai,bv,bi) (((av) < (bv)) || ((av) == (bv) && (ai) < (bi)))

// insert (d,ii) into sorted triple (v0<=v1<=v2 by LT)
__device__ __forceinline__ void ins3(float d, int ii,
    float& v0, int& i0, float& v1, int& i1, float& v2, int& i2){
  if (LT(d, ii, v2, i2)){
    if (LT(d, ii, v1, i1)){
      v2 = v1; i2 = i1;
      if (LT(d, ii, v0, i0)){ v1 = v0; i1 = i0; v0 = d; i0 = ii; }
      else                  { v1 = d;  i1 = ii; }
    } else { v2 = d; i2 = ii; }
  }
}

// butterfly-merge step: merge my sorted triple with lane^off's triple
__device__ __forceinline__ void mrg3(int off,
    float& v0, int& i0, float& v1, int& i1, float& v2, int& i2){
  float b0 = __shfl_xor(v0, off), b1 = __shfl_xor(v1, off), b2 = __shfl_xor(v2, off);
  int   j0 = __shfl_xor(i0, off), j1 = __shfl_xor(i1, off), j2 = __shfl_xor(i2, off);
  float a0 = v0, a1 = v1, a2 = v2; int x0 = i0, x1 = i1, x2 = i2;
  float r0, r1, r2; int s0, s1, s2;
  if (LT(a0, x0, b0, j0)){ r0 = a0; s0 = x0; a0 = a1; x0 = x1; a1 = a2; x1 = x2; a2 = __builtin_inff(); x2 = 0x7fffffff; }
  else                   { r0 = b0; s0 = j0; b0 = b1; j0 = j1; b1 = b2; j1 = j2; b2 = __builtin_inff(); j2 = 0x7fffffff; }
  if (LT(a0, x0, b0, j0)){ r1 = a0; s1 = x0; a0 = a1; x0 = x1; a1 = a2; x1 = x2; a2 = __builtin_inff(); x2 = 0x7fffffff; }
  else                   { r1 = b0; s1 = j0; b0 = b1; j0 = j1; b1 = b2; j1 = j2; b2 = __builtin_inff(); j2 = 0x7fffffff; }
  if (LT(a0, x0, b0, j0)){ r2 = a0; s2 = x0; }
  else                   { r2 = b0; s2 = j0; }
  v0 = r0; i0 = s0; v1 = r1; i1 = s1; v2 = r2; i2 = s2;
}

// ---------------- prep: fp32 -> bf16 (rne), K-chunk-major layout + fp32 row norms ----------------
__device__ __forceinline__ unsigned short f2bf_rne(float f){
  unsigned u = __float_as_uint(f);
  unsigned r = 0x7fffu + ((u >> 16) & 1u);
  return (unsigned short)((u + r) >> 16);
}

__global__ __launch_bounds__(256) void k_prep(
    const float* __restrict__ X, const float* __restrict__ E,
    short* __restrict__ XT, short* __restrict__ ET,
    float* __restrict__ xnorm, float* __restrict__ enorm)
{
  int b = blockIdx.x; int tid = threadIdx.x;
  const float* src; short* dst; float* nrm; int r0, NR;
  if (b < N_ROWS / 8){ r0 = b * 8;                src = X; dst = XT; nrm = xnorm; NR = N_ROWS; }
  else               { r0 = (b - N_ROWS / 8) * 8; src = E; dst = ET; nrm = enorm; NR = N_EMB;  }
  int e = tid & 7, rsub = (tid >> 3) & 7, qg = tid >> 6;   // 8e x 8row x 4qg
  int row = r0 + rsub;
  float s = 0.f;
  #pragma unroll
  for (int qq = 0; qq < 8; qq++){
    int q = qg * 8 + qq;                 // k-chunk [0,32) covering K=256
    float x = src[(size_t)row * C_DIM + q * 8 + e];
    dst[((size_t)q * NR + row) * 8 + e] = (short)f2bf_rne(x);
    s += x * x;
  }
  __shared__ float red[8][33];
  red[rsub][qg * 8 + e] = s;
  __syncthreads();
  if (tid < 8){
    float t = 0.f;
    #pragma unroll
    for (int i = 0; i < 32; i++) t += red[tid][i];
    nrm[r0 + tid] = t;
  }
}

// ---------------- GEMM (R11-exact): BM=256 BN=256 BK=32, 8 waves, writes distances only ----------------
__device__ __forceinline__ void gload16(void* lds, const void* g){
  __builtin_amdgcn_global_load_lds(
      (const __attribute__((address_space(1))) void*)g,
      (__attribute__((address_space(3))) void*)lds, 16, 0, 0);
}

__global__ __launch_bounds__(512, 2) void k_gemm(
    const short* __restrict__ XT, const short* __restrict__ ET,
    const float* __restrict__ xnorm, const float* __restrict__ enorm,
    float* __restrict__ out)
{
  __shared__ __align__(16) short As[2][4 * 256 * 8];
  __shared__ __align__(16) short Bs[2][4 * 256 * 8];
  int tid = threadIdx.x;
  int lane = tid & 63, w = tid >> 6;
  int wr = w >> 2, wc = w & 3;          // wave grid 2M x 4N; wave-tile 128 x 64
  int id = blockIdx.x;                  // 2048 blocks = 64 bm x 32 bn
  int x = id & 7, jj = id >> 3, c = jj >> 5, u = jj & 31;
  int bm = c * 8 + (u >> 2);            // [0,64)
  int bn = x * 4 + (u & 3);             // [0,32)

  f32x4 acc[8][4];
  #pragma unroll
  for (int m = 0; m < 8; m++)
    #pragma unroll
    for (int n = 0; n < 4; n++) acc[m][n] = (f32x4){0.f, 0.f, 0.f, 0.f};

  auto stage = [&](int buf, int kt){
    #pragma unroll
    for (int i = 0; i < 4; i++){
      int p = w * 4 + i;                // wave-uniform
      if (p < 16){
        int q = p >> 2, qr = p & 3;
        gload16(&As[buf][(q * 256 + qr * 64) * 8],
                XT + ((size_t)(kt * 4 + q) * N_ROWS + (size_t)bm * 256 + qr * 64 + lane) * 8);
      } else {
        int pb = p - 16; int q = pb >> 2, qr = pb & 3;
        gload16(&Bs[buf][(q * 256 + qr * 64) * 8],
                ET + ((size_t)(kt * 4 + q) * N_EMB + (size_t)bn * 256 + qr * 64 + lane) * 8);
      }
    }
  };

  int r15 = lane & 15, lg4 = lane >> 4;

  stage(0, 0); stage(1, 1);             // 8 loads/wave in flight

  #pragma unroll
  for (int t = 0; t < NKT; ++t){
    const int buf = t & 1;
    if (t < NKT - 1) { asm volatile("s_waitcnt vmcnt(4)" ::: "memory"); }
    else             { asm volatile("s_waitcnt vmcnt(0)" ::: "memory"); }
    __builtin_amdgcn_s_barrier();       // barrier 1: tile t fully in LDS

    bf16x8 af[8], bf[4];
    {
      int q = lg4;
      #pragma unroll
      for (int m = 0; m < 8; m++)
        af[m] = *(const bf16x8*)&As[buf][(q * 256 + wr * 128 + m * 16 + r15) * 8];
      #pragma unroll
      for (int n = 0; n < 4; n++)
        bf[n] = *(const bf16x8*)&Bs[buf][(q * 256 + wc * 64 + n * 16 + r15) * 8];
    }
    __builtin_amdgcn_s_setprio(1);
    #pragma unroll
    for (int m = 0; m < 4; m++)
      #pragma unroll
      for (int n = 0; n < 4; n++)
        acc[m][n] = __builtin_amdgcn_mfma_f32_16x16x32_bf16(af[m], bf[n], acc[m][n], 0, 0, 0);
    __builtin_amdgcn_s_setprio(0);

    asm volatile("s_waitcnt lgkmcnt(0)" ::: "memory");
    __builtin_amdgcn_sched_barrier(0);
    __builtin_amdgcn_s_barrier();       // barrier 2: all waves done reading buf
    if (t < NKT - 2) stage(buf, t + 2);

    __builtin_amdgcn_s_setprio(1);
    #pragma unroll
    for (int m = 4; m < 8; m++)
      #pragma unroll
      for (int n = 0; n < 4; n++)
        acc[m][n] = __builtin_amdgcn_mfma_f32_16x16x32_bf16(af[m], bf[n], acc[m][n], 0, 0, 0);
    __builtin_amdgcn_s_setprio(0);
  }

  // epilogue: dist = ||x||^2 + ||e||^2 - 2*dot  (C/D map: col=lane&15, row=(lane>>4)*4+j)
  int lc = lane & 15;
  #pragma unroll
  for (int m = 0; m < 8; m++){
    int rb = bm * 256 + wr * 128 + m * 16 + lg4 * 4;
    float xn0 = xnorm[rb], xn1 = xnorm[rb+1], xn2 = xnorm[rb+2], xn3 = xnorm[rb+3];
    #pragma unroll
    for (int n = 0; n < 4; n++){
      int col = bn * 256 + wc * 64 + n * 16 + lc;
      float en = enorm[col];
      out[OFF_DIST + (size_t)(rb + 0) * N_EMB + col] = xn0 + en - 2.0f * acc[m][n][0];
      out[OFF_DIST + (size_t)(rb + 1) * N_EMB + col] = xn1 + en - 2.0f * acc[m][n][1];
      out[OFF_DIST + (size_t)(rb + 2) * N_EMB + col] = xn2 + en - 2.0f * acc[m][n][2];
      out[OFF_DIST + (size_t)(rb + 3) * N_EMB + col] = xn3 + en - 2.0f * acc[m][n][3];
    }
  }
}

// ---------------- top-3 by RECOMPUTE (swapped-operand MFMA, no LDS, no barriers) ----------------
// Numerically PROVEN (R13/R14 absmax == R11). R13/R14 were scratch-bound: the xf ARRAY was never
// SROA-promoted (rule #20 — loop-indexed alloca goes to scratch; launch_bounds can't fix it).
// Fix: NO arrays at all — 32 named fragments + named acc chains + named triples, macro-expanded.
__global__ __launch_bounds__(256, 1) void k_t3(
    const short* __restrict__ XT, const short* __restrict__ ET,
    const float* __restrict__ enorm, f32x2* __restrict__ partial)
{
  int tid = threadIdx.x; int lane = tid & 63, w = tid >> 6;
  int b = blockIdx.x;
  int xg = b >> 1, h = b & 1;           // X-group (64 rows), E-half
  int r15 = lane & 15, lg4 = lane >> 4;
  int xbase = xg * 64;

  // 32 named X fragments (4 X-sets x 8 k-steps), ~128 VGPRs, register-resident by construction
#define XLOAD(xs, ks) \
  bf16x8 xf_##xs##_##ks = *(const bf16x8*)&XT[((size_t)((ks) * 4 + lg4) * N_ROWS + xbase + (xs) * 16 + r15) * 8];
#define XLOADROW(xs) XLOAD(xs,0) XLOAD(xs,1) XLOAD(xs,2) XLOAD(xs,3) XLOAD(xs,4) XLOAD(xs,5) XLOAD(xs,6) XLOAD(xs,7)
  XLOADROW(0) XLOADROW(1) XLOADROW(2) XLOADROW(3)

#define DEFTRIP(xs) \
  float tv0_##xs = __builtin_inff(), tv1_##xs = __builtin_inff(), tv2_##xs = __builtin_inff(); \
  int   ti0_##xs = 0x7fffffff, ti1_##xs = 0x7fffffff, ti2_##xs = 0x7fffffff;
  DEFTRIP(0) DEFTRIP(1) DEFTRIP(2) DEFTRIP(3)

  int eb0 = h * 4096 + w * 1024;        // this wave's 1024-E slice, 64 tiles of 16
  #pragma unroll 2
  for (int et = 0; et < 64; ++et){
    int eb = eb0 + et * 16;
    f32x4 a_0 = (f32x4){0.f,0.f,0.f,0.f}, a_1 = (f32x4){0.f,0.f,0.f,0.f};
    f32x4 a_2 = (f32x4){0.f,0.f,0.f,0.f}, a_3 = (f32x4){0.f,0.f,0.f,0.f};
#define KSTEP(ks) { \
    bf16x8 ef = *(const bf16x8*)&ET[((size_t)((ks) * 4 + lg4) * N_EMB + eb + r15) * 8]; \
    a_0 = __builtin_amdgcn_mfma_f32_16x16x32_bf16(ef, xf_0_##ks, a_0, 0, 0, 0); \
    a_1 = __builtin_amdgcn_mfma_f32_16x16x32_bf16(ef, xf_1_##ks, a_1, 0, 0, 0); \
    a_2 = __builtin_amdgcn_mfma_f32_16x16x32_bf16(ef, xf_2_##ks, a_2, 0, 0, 0); \
    a_3 = __builtin_amdgcn_mfma_f32_16x16x32_bf16(ef, xf_3_##ks, a_3, 0, 0, 0); }
    KSTEP(0) KSTEP(1) KSTEP(2) KSTEP(3) KSTEP(4) KSTEP(5) KSTEP(6) KSTEP(7)
#define INSJ(j) { \
    int er = eb + lg4 * 4 + (j); \
    float en = enorm[er]; \
    ins3(en - 2.0f * a_0[j], er, tv0_0, ti0_0, tv1_0, ti1_0, tv2_0, ti2_0); \
    ins3(en - 2.0f * a_1[j], er, tv0_1, ti0_1, tv1_1, ti1_1, tv2_1, ti2_1); \
    ins3(en - 2.0f * a_2[j], er, tv0_2, ti0_2, tv1_2, ti1_2, tv2_2, ti2_2); \
    ins3(en - 2.0f * a_3[j], er, tv0_3, ti0_3, tv1_3, ti1_3, tv2_3, ti2_3); }
    INSJ(0) INSJ(1) INSJ(2) INSJ(3)
  }
  // merge the 4 lg4 groups (disjoint E subsets, same X-row per r15): xor 16 then 32
#define MERGESTORE(xs) { \
    mrg3(16, tv0_##xs, ti0_##xs, tv1_##xs, ti1_##xs, tv2_##xs, ti2_##xs); \
    mrg3(32, tv0_##xs, ti0_##xs, tv1_##xs, ti1_##xs, tv2_##xs, ti2_##xs); \
    if (lane < 16){ \
      int row = xbase + (xs) * 16 + lane; \
      size_t base = ((size_t)row * 8 + h * 4 + w) * 3; \
      partial[base + 0] = (f32x2){tv0_##xs, __int_as_float(ti0_##xs)}; \
      partial[base + 1] = (f32x2){tv1_##xs, __int_as_float(ti1_##xs)}; \
      partial[base + 2] = (f32x2){tv2_##xs, __int_as_float(ti2_##xs)}; } }
  MERGESTORE(0) MERGESTORE(1) MERGESTORE(2) MERGESTORE(3)
}

// ---------------- merge partials -> top3 + quantize + loss partials (R13-proven) ----------------
__global__ __launch_bounds__(256) void k_mq(
    const f32x2* __restrict__ partial, const float* __restrict__ X, const float* __restrict__ E,
    float* out, int* __restrict__ counts, float* __restrict__ partials)
{
  int wid = threadIdx.x >> 6, lane = threadIdx.x & 63;
  int row = blockIdx.x * 4 + wid;
  const f32x2* pr = partial + (size_t)row * 24;   // 8 E-slices x 3 sorted triples
  float v0 = __builtin_inff(), v1 = __builtin_inff(), v2 = __builtin_inff();
  int   i0 = 0x7fffffff,       i1 = 0x7fffffff,       i2 = 0x7fffffff;
  if (lane < 24){ f32x2 p = pr[lane]; ins3(p[0], __float_as_int(p[1]), v0, i0, v1, i1, v2, i2); }
  #pragma unroll
  for (int off = 1; off < 64; off <<= 1)
    mrg3(off, v0, i0, v1, i1, v2, i2);
  // butterfly all-reduce: every lane now holds the global sorted triple
  if (lane == 0){
    out[OFF_IDX + (size_t)row * 3 + 0] = (float)i0;
    out[OFF_IDX + (size_t)row * 3 + 1] = (float)i1;
    out[OFF_IDX + (size_t)row * 3 + 2] = (float)i2;
    atomicAdd(&counts[i0], 1); atomicAdd(&counts[i1], 1); atomicAdd(&counts[i2], 1);
  }
  // quantize + straight-through + loss partial (literal STE: x + (e - x))
  int c4 = lane * 4;
  f32x4 x4 = *(const f32x4*)&X[(size_t)row * C_DIM + c4];
  int idx[3] = {i0, i1, i2};
  float lsum = 0.f;
  #pragma unroll
  for (int t = 0; t < 3; t++){
    f32x4 e4 = *(const f32x4*)&E[(size_t)idx[t] * C_DIM + c4];
    #pragma unroll
    for (int q = 0; q < 4; q++){
      float diff = e4[q] - x4[q];
      out[OFF_Q + ((size_t)row * 3 + t) * C_DIM + c4 + q] = x4[q] + diff;
      lsum += diff * diff;
    }
  }
  #pragma unroll
  for (int off = 32; off > 0; off >>= 1) lsum += __shfl_down(lsum, off);
  if (lane == 0) partials[row] = lsum;
}

// ---------------- scalars: loss + perplexity ----------------
__global__ __launch_bounds__(256) void k_final(
    const float* __restrict__ partials, const int* __restrict__ counts,
    float* __restrict__ out)
{
  int t = threadIdx.x;
  float ls = 0.f;
  for (int i = t; i < N_ROWS; i += 256) ls += partials[i];
  float es = 0.f;
  for (int i = t; i < N_EMB; i += 256){
    float p = (float)counts[i] * (1.0f / 16384.0f);
    es += p * logf(p + 1e-10f);
  }
  __shared__ float r1[256], r2[256];
  r1[t] = ls; r2[t] = es; __syncthreads();
  for (int s = 128; s > 0; s >>= 1){
    if (t < s){ r1[t] += r1[t + s]; r2[t] += r2[t + s]; }
    __syncthreads();
  }
  if (t == 0){
    out[OFF_LOSS] = 0.25f * r1[0] / 12582912.0f;
    out[OFF_PERP] = expf(-r2[0]);
  }
}

extern "C" void kernel_launch(void* const* d_in, const int* in_sizes, int n_in,
                              void* d_out, int out_size, void* d_ws, size_t ws_size,
                              hipStream_t stream)
{
  const float* X = (const float*)d_in[0];
  const float* E = (const float*)d_in[1];
  float* out = (float*)d_out;
  char* ws = (char*)d_ws;
  // ws layout (bytes), total ~16 MB
  short* XT       = (short*)(ws + 0);          // 8388608   (K-chunk-major bf16)
  short* ET       = (short*)(ws + 8388608);    // 4194304   (K-chunk-major bf16)
  float* xnorm    = (float*)(ws + 12582912);   // 65536
  float* enorm    = (float*)(ws + 12648448);   // 32768
  f32x2* partial  = (f32x2*)(ws + 12681216);   // 16384*8*3*8 = 3145728
  int*   counts   = (int*)  (ws + 15826944);   // 32768
  float* partials = (float*)(ws + 15859712);   // 65536

  hipMemsetAsync(counts, 0, N_EMB * sizeof(int), stream);
  k_prep<<<(N_ROWS + N_EMB) / 8, 256, 0, stream>>>(X, E, XT, ET, xnorm, enorm);
  k_gemm<<<2048, 512, 0, stream>>>(XT, ET, xnorm, enorm, out);
  k_t3<<<512, 256, 0, stream>>>(XT, ET, enorm, partial);
  k_mq<<<N_ROWS / 4, 256, 0, stream>>>(partial, X, E, out, counts, partials);
  k_final<<<1, 256, 0, stream>>>(partials, counts, out);
}

// Round 16
// 790.361 us; speedup vs baseline: 1.0024x; 1.0024x over previous
//
#include <hip/hip_runtime.h>
#include <stdint.h>

// Problem constants
#define N_ROWS 16384   // 16*1024 flattened input rows
#define N_EMB  8192    // codebook size
#define C_DIM  256     // embedding dim
#define NKT    8       // pure-bf16 GEMM: K=256, 8 K-tiles of 32 (R9-validated)

// d_out layout (float element offsets), outputs concatenated in return order:
// loss(1), quantized_st(16*1024*3*256), perplexity(1), encoding_indices(16384*3), distances(16384*8192)
#define OFF_LOSS 0ull
#define OFF_Q    1ull
#define OFF_PERP 12582913ull
#define OFF_IDX  12582914ull
#define OFF_DIST 12632066ull

typedef short bf16x8 __attribute__((ext_vector_type(8)));
typedef float f32x4  __attribute__((ext_vector_type(4)));
typedef float f32x2  __attribute__((ext_vector_type(2)));

#define LT(av,ai,bv,bi) (((av) < (bv)) || ((av) == (bv) && (ai) < (bi)))

// insert (d,ii) into sorted triple (v0<=v1<=v2 by LT)
__device__ __forceinline__ void ins3(float d, int ii,
    float& v0, int& i0, float& v1, int& i1, float& v2, int& i2){
  if (LT(d, ii, v2, i2)){
    if (LT(d, ii, v1, i1)){
      v2 = v1; i2 = i1;
      if (LT(d, ii, v0, i0)){ v1 = v0; i1 = i0; v0 = d; i0 = ii; }
      else                  { v1 = d;  i1 = ii; }
    } else { v2 = d; i2 = ii; }
  }
}

// butterfly-merge step: merge my sorted triple with lane^off's triple
__device__ __forceinline__ void mrg3(int off,
    float& v0, int& i0, float& v1, int& i1, float& v2, int& i2){
  float b0 = __shfl_xor(v0, off), b1 = __shfl_xor(v1, off), b2 = __shfl_xor(v2, off);
  int   j0 = __shfl_xor(i0, off), j1 = __shfl_xor(i1, off), j2 = __shfl_xor(i2, off);
  float a0 = v0, a1 = v1, a2 = v2; int x0 = i0, x1 = i1, x2 = i2;
  float r0, r1, r2; int s0, s1, s2;
  if (LT(a0, x0, b0, j0)){ r0 = a0; s0 = x0; a0 = a1; x0 = x1; a1 = a2; x1 = x2; a2 = __builtin_inff(); x2 = 0x7fffffff; }
  else                   { r0 = b0; s0 = j0; b0 = b1; j0 = j1; b1 = b2; j1 = j2; b2 = __builtin_inff(); j2 = 0x7fffffff; }
  if (LT(a0, x0, b0, j0)){ r1 = a0; s1 = x0; a0 = a1; x0 = x1; a1 = a2; x1 = x2; a2 = __builtin_inff(); x2 = 0x7fffffff; }
  else                   { r1 = b0; s1 = j0; b0 = b1; j0 = j1; b1 = b2; j1 = j2; b2 = __builtin_inff(); j2 = 0x7fffffff; }
  if (LT(a0, x0, b0, j0)){ r2 = a0; s2 = x0; }
  else                   { r2 = b0; s2 = j0; }
  v0 = r0; i0 = s0; v1 = r1; i1 = s1; v2 = r2; i2 = s2;
}

// ---------------- prep: fp32 -> bf16 (rne), K-chunk-major layout + fp32 row norms ----------------
__device__ __forceinline__ unsigned short f2bf_rne(float f){
  unsigned u = __float_as_uint(f);
  unsigned r = 0x7fffu + ((u >> 16) & 1u);
  return (unsigned short)((u + r) >> 16);
}

__global__ __launch_bounds__(256) void k_prep(
    const float* __restrict__ X, const float* __restrict__ E,
    short* __restrict__ XT, short* __restrict__ ET,
    float* __restrict__ xnorm, float* __restrict__ enorm)
{
  int b = blockIdx.x; int tid = threadIdx.x;
  const float* src; short* dst; float* nrm; int r0, NR;
  if (b < N_ROWS / 8){ r0 = b * 8;                src = X; dst = XT; nrm = xnorm; NR = N_ROWS; }
  else               { r0 = (b - N_ROWS / 8) * 8; src = E; dst = ET; nrm = enorm; NR = N_EMB;  }
  int e = tid & 7, rsub = (tid >> 3) & 7, qg = tid >> 6;   // 8e x 8row x 4qg
  int row = r0 + rsub;
  float s = 0.f;
  #pragma unroll
  for (int qq = 0; qq < 8; qq++){
    int q = qg * 8 + qq;                 // k-chunk [0,32) covering K=256
    float x = src[(size_t)row * C_DIM + q * 8 + e];
    dst[((size_t)q * NR + row) * 8 + e] = (short)f2bf_rne(x);
    s += x * x;
  }
  __shared__ float red[8][33];
  red[rsub][qg * 8 + e] = s;
  __syncthreads();
  if (tid < 8){
    float t = 0.f;
    #pragma unroll
    for (int i = 0; i < 32; i++) t += red[tid][i];
    nrm[r0 + tid] = t;
  }
}

// ---------------- GEMM (R11-exact): BM=256 BN=256 BK=32, 8 waves, writes distances only ----------------
__device__ __forceinline__ void gload16(void* lds, const void* g){
  __builtin_amdgcn_global_load_lds(
      (const __attribute__((address_space(1))) void*)g,
      (__attribute__((address_space(3))) void*)lds, 16, 0, 0);
}

__global__ __launch_bounds__(512, 2) void k_gemm(
    const short* __restrict__ XT, const short* __restrict__ ET,
    const float* __restrict__ xnorm, const float* __restrict__ enorm,
    float* __restrict__ out)
{
  __shared__ __align__(16) short As[2][4 * 256 * 8];
  __shared__ __align__(16) short Bs[2][4 * 256 * 8];
  int tid = threadIdx.x;
  int lane = tid & 63, w = tid >> 6;
  int wr = w >> 2, wc = w & 3;          // wave grid 2M x 4N; wave-tile 128 x 64
  int id = blockIdx.x;                  // 2048 blocks = 64 bm x 32 bn
  int x = id & 7, jj = id >> 3, c = jj >> 5, u = jj & 31;
  int bm = c * 8 + (u >> 2);            // [0,64)
  int bn = x * 4 + (u & 3);             // [0,32)

  f32x4 acc[8][4];
  #pragma unroll
  for (int m = 0; m < 8; m++)
    #pragma unroll
    for (int n = 0; n < 4; n++) acc[m][n] = (f32x4){0.f, 0.f, 0.f, 0.f};

  auto stage = [&](int buf, int kt){
    #pragma unroll
    for (int i = 0; i < 4; i++){
      int p = w * 4 + i;                // wave-uniform
      if (p < 16){
        int q = p >> 2, qr = p & 3;
        gload16(&As[buf][(q * 256 + qr * 64) * 8],
                XT + ((size_t)(kt * 4 + q) * N_ROWS + (size_t)bm * 256 + qr * 64 + lane) * 8);
      } else {
        int pb = p - 16; int q = pb >> 2, qr = pb & 3;
        gload16(&Bs[buf][(q * 256 + qr * 64) * 8],
                ET + ((size_t)(kt * 4 + q) * N_EMB + (size_t)bn * 256 + qr * 64 + lane) * 8);
      }
    }
  };

  int r15 = lane & 15, lg4 = lane >> 4;

  stage(0, 0); stage(1, 1);             // 8 loads/wave in flight

  #pragma unroll
  for (int t = 0; t < NKT; ++t){
    const int buf = t & 1;
    if (t < NKT - 1) { asm volatile("s_waitcnt vmcnt(4)" ::: "memory"); }
    else             { asm volatile("s_waitcnt vmcnt(0)" ::: "memory"); }
    __builtin_amdgcn_s_barrier();       // barrier 1: tile t fully in LDS

    bf16x8 af[8], bf[4];
    {
      int q = lg4;
      #pragma unroll
      for (int m = 0; m < 8; m++)
        af[m] = *(const bf16x8*)&As[buf][(q * 256 + wr * 128 + m * 16 + r15) * 8];
      #pragma unroll
      for (int n = 0; n < 4; n++)
        bf[n] = *(const bf16x8*)&Bs[buf][(q * 256 + wc * 64 + n * 16 + r15) * 8];
    }
    __builtin_amdgcn_s_setprio(1);
    #pragma unroll
    for (int m = 0; m < 4; m++)
      #pragma unroll
      for (int n = 0; n < 4; n++)
        acc[m][n] = __builtin_amdgcn_mfma_f32_16x16x32_bf16(af[m], bf[n], acc[m][n], 0, 0, 0);
    __builtin_amdgcn_s_setprio(0);

    asm volatile("s_waitcnt lgkmcnt(0)" ::: "memory");
    __builtin_amdgcn_sched_barrier(0);
    __builtin_amdgcn_s_barrier();       // barrier 2: all waves done reading buf
    if (t < NKT - 2) stage(buf, t + 2);

    __builtin_amdgcn_s_setprio(1);
    #pragma unroll
    for (int m = 4; m < 8; m++)
      #pragma unroll
      for (int n = 0; n < 4; n++)
        acc[m][n] = __builtin_amdgcn_mfma_f32_16x16x32_bf16(af[m], bf[n], acc[m][n], 0, 0, 0);
    __builtin_amdgcn_s_setprio(0);
  }

  // epilogue: dist = ||x||^2 + ||e||^2 - 2*dot  (C/D map: col=lane&15, row=(lane>>4)*4+j)
  int lc = lane & 15;
  #pragma unroll
  for (int m = 0; m < 8; m++){
    int rb = bm * 256 + wr * 128 + m * 16 + lg4 * 4;
    float xn0 = xnorm[rb], xn1 = xnorm[rb+1], xn2 = xnorm[rb+2], xn3 = xnorm[rb+3];
    #pragma unroll
    for (int n = 0; n < 4; n++){
      int col = bn * 256 + wc * 64 + n * 16 + lc;
      float en = enorm[col];
      out[OFF_DIST + (size_t)(rb + 0) * N_EMB + col] = xn0 + en - 2.0f * acc[m][n][0];
      out[OFF_DIST + (size_t)(rb + 1) * N_EMB + col] = xn1 + en - 2.0f * acc[m][n][1];
      out[OFF_DIST + (size_t)(rb + 2) * N_EMB + col] = xn2 + en - 2.0f * acc[m][n][2];
      out[OFF_DIST + (size_t)(rb + 3) * N_EMB + col] = xn3 + en - 2.0f * acc[m][n][3];
    }
  }
}

// ---------------- top-3 by RECOMPUTE (swapped-operand MFMA, no LDS, no barriers) ----------------
// Numerically PROVEN (R13/R14/R15 absmax == R11). R13-R15 were stalled on REMATERIALIZED loads:
// the allocator (VGPR 92-104) re-loads the loop-invariant X fragments from global inside the loop
// instead of holding them (loads from __restrict__ are trivially remat-able). Fix: pin each
// fragment with an opaque asm "+v" — an inline-asm result CANNOT be rematerialized, so the 128
// VGPRs of X stay register-resident for the whole E-sweep (budget 512 via launch_bounds(256,1)).
__global__ __launch_bounds__(256, 1) void k_t3(
    const short* __restrict__ XT, const short* __restrict__ ET,
    const float* __restrict__ enorm, f32x2* __restrict__ partial)
{
  int tid = threadIdx.x; int lane = tid & 63, w = tid >> 6;
  int b = blockIdx.x;
  int xg = b >> 1, h = b & 1;           // X-group (64 rows), E-half
  int r15 = lane & 15, lg4 = lane >> 4;
  int xbase = xg * 64;

  // 32 named X fragments (4 X-sets x 8 k-steps) = 128 VGPRs
#define XLOAD(xs, ks) \
  bf16x8 xf_##xs##_##ks = *(const bf16x8*)&XT[((size_t)((ks) * 4 + lg4) * N_ROWS + xbase + (xs) * 16 + r15) * 8];
#define XLOADROW(xs) XLOAD(xs,0) XLOAD(xs,1) XLOAD(xs,2) XLOAD(xs,3) XLOAD(xs,4) XLOAD(xs,5) XLOAD(xs,6) XLOAD(xs,7)
  XLOADROW(0) XLOADROW(1) XLOADROW(2) XLOADROW(3)

  // anti-remat pin: value becomes an opaque asm result -> must stay live in registers
#define XPIN(xs, ks) asm volatile("" : "+v"(xf_##xs##_##ks));
#define XPINROW(xs) XPIN(xs,0) XPIN(xs,1) XPIN(xs,2) XPIN(xs,3) XPIN(xs,4) XPIN(xs,5) XPIN(xs,6) XPIN(xs,7)
  XPINROW(0) XPINROW(1) XPINROW(2) XPINROW(3)

#define DEFTRIP(xs) \
  float tv0_##xs = __builtin_inff(), tv1_##xs = __builtin_inff(), tv2_##xs = __builtin_inff(); \
  int   ti0_##xs = 0x7fffffff, ti1_##xs = 0x7fffffff, ti2_##xs = 0x7fffffff;
  DEFTRIP(0) DEFTRIP(1) DEFTRIP(2) DEFTRIP(3)

  int eb0 = h * 4096 + w * 1024;        // this wave's 1024-E slice, 64 tiles of 16
  #pragma unroll 2
  for (int et = 0; et < 64; ++et){
    int eb = eb0 + et * 16;
    f32x4 a_0 = (f32x4){0.f,0.f,0.f,0.f}, a_1 = (f32x4){0.f,0.f,0.f,0.f};
    f32x4 a_2 = (f32x4){0.f,0.f,0.f,0.f}, a_3 = (f32x4){0.f,0.f,0.f,0.f};
#define KSTEP(ks) { \
    bf16x8 ef = *(const bf16x8*)&ET[((size_t)((ks) * 4 + lg4) * N_EMB + eb + r15) * 8]; \
    a_0 = __builtin_amdgcn_mfma_f32_16x16x32_bf16(ef, xf_0_##ks, a_0, 0, 0, 0); \
    a_1 = __builtin_amdgcn_mfma_f32_16x16x32_bf16(ef, xf_1_##ks, a_1, 0, 0, 0); \
    a_2 = __builtin_amdgcn_mfma_f32_16x16x32_bf16(ef, xf_2_##ks, a_2, 0, 0, 0); \
    a_3 = __builtin_amdgcn_mfma_f32_16x16x32_bf16(ef, xf_3_##ks, a_3, 0, 0, 0); }
    KSTEP(0) KSTEP(1) KSTEP(2) KSTEP(3) KSTEP(4) KSTEP(5) KSTEP(6) KSTEP(7)
#define INSJ(j) { \
    int er = eb + lg4 * 4 + (j); \
    float en = enorm[er]; \
    ins3(en - 2.0f * a_0[j], er, tv0_0, ti0_0, tv1_0, ti1_0, tv2_0, ti2_0); \
    ins3(en - 2.0f * a_1[j], er, tv0_1, ti0_1, tv1_1, ti1_1, tv2_1, ti2_1); \
    ins3(en - 2.0f * a_2[j], er, tv0_2, ti0_2, tv1_2, ti1_2, tv2_2, ti2_2); \
    ins3(en - 2.0f * a_3[j], er, tv0_3, ti0_3, tv1_3, ti1_3, tv2_3, ti2_3); }
    INSJ(0) INSJ(1) INSJ(2) INSJ(3)
  }
  // merge the 4 lg4 groups (disjoint E subsets, same X-row per r15): xor 16 then 32
#define MERGESTORE(xs) { \
    mrg3(16, tv0_##xs, ti0_##xs, tv1_##xs, ti1_##xs, tv2_##xs, ti2_##xs); \
    mrg3(32, tv0_##xs, ti0_##xs, tv1_##xs, ti1_##xs, tv2_##xs, ti2_##xs); \
    if (lane < 16){ \
      int row = xbase + (xs) * 16 + lane; \
      size_t base = ((size_t)row * 8 + h * 4 + w) * 3; \
      partial[base + 0] = (f32x2){tv0_##xs, __int_as_float(ti0_##xs)}; \
      partial[base + 1] = (f32x2){tv1_##xs, __int_as_float(ti1_##xs)}; \
      partial[base + 2] = (f32x2){tv2_##xs, __int_as_float(ti2_##xs)}; } }
  MERGESTORE(0) MERGESTORE(1) MERGESTORE(2) MERGESTORE(3)
}

// ---------------- merge partials -> top3 + quantize + loss partials (R13-proven) ----------------
__global__ __launch_bounds__(256) void k_mq(
    const f32x2* __restrict__ partial, const float* __restrict__ X, const float* __restrict__ E,
    float* out, int* __restrict__ counts, float* __restrict__ partials)
{
  int wid = threadIdx.x >> 6, lane = threadIdx.x & 63;
  int row = blockIdx.x * 4 + wid;
  const f32x2* pr = partial + (size_t)row * 24;   // 8 E-slices x 3 sorted triples
  float v0 = __builtin_inff(), v1 = __builtin_inff(), v2 = __builtin_inff();
  int   i0 = 0x7fffffff,       i1 = 0x7fffffff,       i2 = 0x7fffffff;
  if (lane < 24){ f32x2 p = pr[lane]; ins3(p[0], __float_as_int(p[1]), v0, i0, v1, i1, v2, i2); }
  #pragma unroll
  for (int off = 1; off < 64; off <<= 1)
    mrg3(off, v0, i0, v1, i1, v2, i2);
  // butterfly all-reduce: every lane now holds the global sorted triple
  if (lane == 0){
    out[OFF_IDX + (size_t)row * 3 + 0] = (float)i0;
    out[OFF_IDX + (size_t)row * 3 + 1] = (float)i1;
    out[OFF_IDX + (size_t)row * 3 + 2] = (float)i2;
    atomicAdd(&counts[i0], 1); atomicAdd(&counts[i1], 1); atomicAdd(&counts[i2], 1);
  }
  // quantize + straight-through + loss partial (literal STE: x + (e - x))
  int c4 = lane * 4;
  f32x4 x4 = *(const f32x4*)&X[(size_t)row * C_DIM + c4];
  int idx[3] = {i0, i1, i2};
  float lsum = 0.f;
  #pragma unroll
  for (int t = 0; t < 3; t++){
    f32x4 e4 = *(const f32x4*)&E[(size_t)idx[t] * C_DIM + c4];
    #pragma unroll
    for (int q = 0; q < 4; q++){
      float diff = e4[q] - x4[q];
      out[OFF_Q + ((size_t)row * 3 + t) * C_DIM + c4 + q] = x4[q] + diff;
      lsum += diff * diff;
    }
  }
  #pragma unroll
  for (int off = 32; off > 0; off >>= 1) lsum += __shfl_down(lsum, off);
  if (lane == 0) partials[row] = lsum;
}

// ---------------- scalars: loss + perplexity ----------------
__global__ __launch_bounds__(256) void k_final(
    const float* __restrict__ partials, const int* __restrict__ counts,
    float* __restrict__ out)
{
  int t = threadIdx.x;
  float ls = 0.f;
  for (int i = t; i < N_ROWS; i += 256) ls += partials[i];
  float es = 0.f;
  for (int i = t; i < N_EMB; i += 256){
    float p = (float)counts[i] * (1.0f / 16384.0f);
    es += p * logf(p + 1e-10f);
  }
  __shared__ float r1[256], r2[256];
  r1[t] = ls; r2[t] = es; __syncthreads();
  for (int s = 128; s > 0; s >>= 1){
    if (t < s){ r1[t] += r1[t + s]; r2[t] += r2[t + s]; }
    __syncthreads();
  }
  if (t == 0){
    out[OFF_LOSS] = 0.25f * r1[0] / 12582912.0f;
    out[OFF_PERP] = expf(-r2[0]);
  }
}

extern "C" void kernel_launch(void* const* d_in, const int* in_sizes, int n_in,
                              void* d_out, int out_size, void* d_ws, size_t ws_size,
                              hipStream_t stream)
{
  const float* X = (const float*)d_in[0];
  const float* E = (const float*)d_in[1];
  float* out = (float*)d_out;
  char* ws = (char*)d_ws;
  // ws layout (bytes), total ~16 MB
  short* XT       = (short*)(ws + 0);          // 8388608   (K-chunk-major bf16)
  short* ET       = (short*)(ws + 8388608);    // 4194304   (K-chunk-major bf16)
  float* xnorm    = (float*)(ws + 12582912);   // 65536
  float* enorm    = (float*)(ws + 12648448);   // 32768
  f32x2* partial  = (f32x2*)(ws + 12681216);   // 16384*8*3*8 = 3145728
  int*   counts   = (int*)  (ws + 15826944);   // 32768
  float* partials = (float*)(ws + 15859712);   // 65536

  hipMemsetAsync(counts, 0, N_EMB * sizeof(int), stream);
  k_prep<<<(N_ROWS + N_EMB) / 8, 256, 0, stream>>>(X, E, XT, ET, xnorm, enorm);
  k_gemm<<<2048, 512, 0, stream>>>(XT, ET, xnorm, enorm, out);
  k_t3<<<512, 256, 0, stream>>>(XT, ET, enorm, partial);
  k_mq<<<N_ROWS / 4, 256, 0, stream>>>(partial, X, E, out, counts, partials);
  k_final<<<1, 256, 0, stream>>>(partials, counts, out);
}

// Round 17
// 770.339 us; speedup vs baseline: 1.0284x; 1.0260x over previous
//
#include <hip/hip_runtime.h>
#include <stdint.h>

// Problem constants
#define N_ROWS 16384   // 16*1024 flattened input rows
#define N_EMB  8192    // codebook size
#define C_DIM  256     // embedding dim
#define NKT    8       // pure-bf16 GEMM: K=256, 8 K-tiles of 32 (R9-validated)

// d_out layout (float element offsets), outputs concatenated in return order:
// loss(1), quantized_st(16*1024*3*256), perplexity(1), encoding_indices(16384*3), distances(16384*8192)
#define OFF_LOSS 0ull
#define OFF_Q    1ull
#define OFF_PERP 12582913ull
#define OFF_IDX  12582914ull
#define OFF_DIST 12632066ull

typedef short bf16x8 __attribute__((ext_vector_type(8)));
typedef float f32x4  __attribute__((ext_vector_type(4)));
typedef float f32x2  __attribute__((ext_vector_type(2)));

#define LT(av,ai,bv,bi) (((av) < (bv)) || ((av) == (bv) && (ai) < (bi)))

// insert (d,ii) into sorted triple (v0<=v1<=v2 by LT)
__device__ __forceinline__ void ins3(float d, int ii,
    float& v0, int& i0, float& v1, int& i1, float& v2, int& i2){
  if (LT(d, ii, v2, i2)){
    if (LT(d, ii, v1, i1)){
      v2 = v1; i2 = i1;
      if (LT(d, ii, v0, i0)){ v1 = v0; i1 = i0; v0 = d; i0 = ii; }
      else                  { v1 = d;  i1 = ii; }
    } else { v2 = d; i2 = ii; }
  }
}

// butterfly-merge step: merge my sorted triple with lane^off's triple
__device__ __forceinline__ void mrg3(int off,
    float& v0, int& i0, float& v1, int& i1, float& v2, int& i2){
  float b0 = __shfl_xor(v0, off), b1 = __shfl_xor(v1, off), b2 = __shfl_xor(v2, off);
  int   j0 = __shfl_xor(i0, off), j1 = __shfl_xor(i1, off), j2 = __shfl_xor(i2, off);
  float a0 = v0, a1 = v1, a2 = v2; int x0 = i0, x1 = i1, x2 = i2;
  float r0, r1, r2; int s0, s1, s2;
  if (LT(a0, x0, b0, j0)){ r0 = a0; s0 = x0; a0 = a1; x0 = x1; a1 = a2; x1 = x2; a2 = __builtin_inff(); x2 = 0x7fffffff; }
  else                   { r0 = b0; s0 = j0; b0 = b1; j0 = j1; b1 = b2; j1 = j2; b2 = __builtin_inff(); j2 = 0x7fffffff; }
  if (LT(a0, x0, b0, j0)){ r1 = a0; s1 = x0; a0 = a1; x0 = x1; a1 = a2; x1 = x2; a2 = __builtin_inff(); x2 = 0x7fffffff; }
  else                   { r1 = b0; s1 = j0; b0 = b1; j0 = j1; b1 = b2; j1 = j2; b2 = __builtin_inff(); j2 = 0x7fffffff; }
  if (LT(a0, x0, b0, j0)){ r2 = a0; s2 = x0; }
  else                   { r2 = b0; s2 = j0; }
  v0 = r0; i0 = s0; v1 = r1; i1 = s1; v2 = r2; i2 = s2;
}

// ---------------- prep: fp32 -> bf16 (rne), K-chunk-major layout + fp32 row norms ----------------
__device__ __forceinline__ unsigned short f2bf_rne(float f){
  unsigned u = __float_as_uint(f);
  unsigned r = 0x7fffu + ((u >> 16) & 1u);
  return (unsigned short)((u + r) >> 16);
}

__global__ __launch_bounds__(256) void k_prep(
    const float* __restrict__ X, const float* __restrict__ E,
    short* __restrict__ XT, short* __restrict__ ET,
    float* __restrict__ xnorm, float* __restrict__ enorm)
{
  int b = blockIdx.x; int tid = threadIdx.x;
  const float* src; short* dst; float* nrm; int r0, NR;
  if (b < N_ROWS / 8){ r0 = b * 8;                src = X; dst = XT; nrm = xnorm; NR = N_ROWS; }
  else               { r0 = (b - N_ROWS / 8) * 8; src = E; dst = ET; nrm = enorm; NR = N_EMB;  }
  int e = tid & 7, rsub = (tid >> 3) & 7, qg = tid >> 6;   // 8e x 8row x 4qg
  int row = r0 + rsub;
  float s = 0.f;
  #pragma unroll
  for (int qq = 0; qq < 8; qq++){
    int q = qg * 8 + qq;                 // k-chunk [0,32) covering K=256
    float x = src[(size_t)row * C_DIM + q * 8 + e];
    dst[((size_t)q * NR + row) * 8 + e] = (short)f2bf_rne(x);
    s += x * x;
  }
  __shared__ float red[8][33];
  red[rsub][qg * 8 + e] = s;
  __syncthreads();
  if (tid < 8){
    float t = 0.f;
    #pragma unroll
    for (int i = 0; i < 32; i++) t += red[tid][i];
    nrm[r0 + tid] = t;
  }
}

// ---------------- GEMM (R11-exact): BM=256 BN=256 BK=32, 8 waves, writes distances only ----------------
__device__ __forceinline__ void gload16(void* lds, const void* g){
  __builtin_amdgcn_global_load_lds(
      (const __attribute__((address_space(1))) void*)g,
      (__attribute__((address_space(3))) void*)lds, 16, 0, 0);
}

__global__ __launch_bounds__(512, 2) void k_gemm(
    const short* __restrict__ XT, const short* __restrict__ ET,
    const float* __restrict__ xnorm, const float* __restrict__ enorm,
    float* __restrict__ out)
{
  __shared__ __align__(16) short As[2][4 * 256 * 8];
  __shared__ __align__(16) short Bs[2][4 * 256 * 8];
  int tid = threadIdx.x;
  int lane = tid & 63, w = tid >> 6;
  int wr = w >> 2, wc = w & 3;          // wave grid 2M x 4N; wave-tile 128 x 64
  int id = blockIdx.x;                  // 2048 blocks = 64 bm x 32 bn
  int x = id & 7, jj = id >> 3, c = jj >> 5, u = jj & 31;
  int bm = c * 8 + (u >> 2);            // [0,64)
  int bn = x * 4 + (u & 3);             // [0,32)

  f32x4 acc[8][4];
  #pragma unroll
  for (int m = 0; m < 8; m++)
    #pragma unroll
    for (int n = 0; n < 4; n++) acc[m][n] = (f32x4){0.f, 0.f, 0.f, 0.f};

  auto stage = [&](int buf, int kt){
    #pragma unroll
    for (int i = 0; i < 4; i++){
      int p = w * 4 + i;                // wave-uniform
      if (p < 16){
        int q = p >> 2, qr = p & 3;
        gload16(&As[buf][(q * 256 + qr * 64) * 8],
                XT + ((size_t)(kt * 4 + q) * N_ROWS + (size_t)bm * 256 + qr * 64 + lane) * 8);
      } else {
        int pb = p - 16; int q = pb >> 2, qr = pb & 3;
        gload16(&Bs[buf][(q * 256 + qr * 64) * 8],
                ET + ((size_t)(kt * 4 + q) * N_EMB + (size_t)bn * 256 + qr * 64 + lane) * 8);
      }
    }
  };

  int r15 = lane & 15, lg4 = lane >> 4;

  stage(0, 0); stage(1, 1);             // 8 loads/wave in flight

  #pragma unroll
  for (int t = 0; t < NKT; ++t){
    const int buf = t & 1;
    if (t < NKT - 1) { asm volatile("s_waitcnt vmcnt(4)" ::: "memory"); }
    else             { asm volatile("s_waitcnt vmcnt(0)" ::: "memory"); }
    __builtin_amdgcn_s_barrier();       // barrier 1: tile t fully in LDS

    bf16x8 af[8], bf[4];
    {
      int q = lg4;
      #pragma unroll
      for (int m = 0; m < 8; m++)
        af[m] = *(const bf16x8*)&As[buf][(q * 256 + wr * 128 + m * 16 + r15) * 8];
      #pragma unroll
      for (int n = 0; n < 4; n++)
        bf[n] = *(const bf16x8*)&Bs[buf][(q * 256 + wc * 64 + n * 16 + r15) * 8];
    }
    __builtin_amdgcn_s_setprio(1);
    #pragma unroll
    for (int m = 0; m < 4; m++)
      #pragma unroll
      for (int n = 0; n < 4; n++)
        acc[m][n] = __builtin_amdgcn_mfma_f32_16x16x32_bf16(af[m], bf[n], acc[m][n], 0, 0, 0);
    __builtin_amdgcn_s_setprio(0);

    asm volatile("s_waitcnt lgkmcnt(0)" ::: "memory");
    __builtin_amdgcn_sched_barrier(0);
    __builtin_amdgcn_s_barrier();       // barrier 2: all waves done reading buf
    if (t < NKT - 2) stage(buf, t + 2);

    __builtin_amdgcn_s_setprio(1);
    #pragma unroll
    for (int m = 4; m < 8; m++)
      #pragma unroll
      for (int n = 0; n < 4; n++)
        acc[m][n] = __builtin_amdgcn_mfma_f32_16x16x32_bf16(af[m], bf[n], acc[m][n], 0, 0, 0);
    __builtin_amdgcn_s_setprio(0);
  }

  // epilogue: dist = ||x||^2 + ||e||^2 - 2*dot  (C/D map: col=lane&15, row=(lane>>4)*4+j)
  int lc = lane & 15;
  #pragma unroll
  for (int m = 0; m < 8; m++){
    int rb = bm * 256 + wr * 128 + m * 16 + lg4 * 4;
    float xn0 = xnorm[rb], xn1 = xnorm[rb+1], xn2 = xnorm[rb+2], xn3 = xnorm[rb+3];
    #pragma unroll
    for (int n = 0; n < 4; n++){
      int col = bn * 256 + wc * 64 + n * 16 + lc;
      float en = enorm[col];
      out[OFF_DIST + (size_t)(rb + 0) * N_EMB + col] = xn0 + en - 2.0f * acc[m][n][0];
      out[OFF_DIST + (size_t)(rb + 1) * N_EMB + col] = xn1 + en - 2.0f * acc[m][n][1];
      out[OFF_DIST + (size_t)(rb + 2) * N_EMB + col] = xn2 + en - 2.0f * acc[m][n][2];
      out[OFF_DIST + (size_t)(rb + 3) * N_EMB + col] = xn3 + en - 2.0f * acc[m][n][3];
    }
  }
}

// ---------------- top-3 by RECOMPUTE, X staged in LDS (no register-residency gamble) ----------------
// Numerically PROVEN (R13-R16 absmax == R11). R13-R16 stalled because the allocator refuses to
// hold X fragments in registers (remat/spill at VGPR~92-104, immune to launch_bounds/naming/pins).
// Fix: X lives in LDS (32 KB, staged once, conflict-free GEMM layout); xf via ds_read_b128.
// Even full per-tile LDS re-read is ~48 cyc/tile/CU vs the 320-cyc MFMA bound -> cannot stall.
__global__ __launch_bounds__(256) void k_t3(
    const short* __restrict__ XT, const short* __restrict__ ET,
    const float* __restrict__ enorm, f32x2* __restrict__ partial)
{
  __shared__ __align__(16) short XL[32 * 64 * 8];   // [q=0..31][row 0..63][8 bf16] = 32 KB
  int tid = threadIdx.x; int lane = tid & 63, w = tid >> 6;
  int b = blockIdx.x;
  int xg = b >> 1, h = b & 1;           // X-group (64 rows), E-half
  int r15 = lane & 15, lg4 = lane >> 4;
  int xbase = xg * 64;

  // stage the X-group: 32 chunks x 1 KB (XT rows are contiguous per chunk); wave w takes 8
  #pragma unroll
  for (int i = 0; i < 8; i++){
    int q = w * 8 + i;                  // wave-uniform
    gload16(&XL[q * 64 * 8], XT + ((size_t)q * N_ROWS + xbase + lane) * 8);
  }
  __syncthreads();                      // full vmcnt drain: XL ready

#define DEFTRIP(xs) \
  float tv0_##xs = __builtin_inff(), tv1_##xs = __builtin_inff(), tv2_##xs = __builtin_inff(); \
  int   ti0_##xs = 0x7fffffff, ti1_##xs = 0x7fffffff, ti2_##xs = 0x7fffffff;
  DEFTRIP(0) DEFTRIP(1) DEFTRIP(2) DEFTRIP(3)

  int eb0 = h * 4096 + w * 1024;        // this wave's 1024-E slice, 64 tiles of 16
  #pragma unroll 2
  for (int et = 0; et < 64; ++et){
    int eb = eb0 + et * 16;
    f32x4 a_0 = (f32x4){0.f,0.f,0.f,0.f}, a_1 = (f32x4){0.f,0.f,0.f,0.f};
    f32x4 a_2 = (f32x4){0.f,0.f,0.f,0.f}, a_3 = (f32x4){0.f,0.f,0.f,0.f};
#define KSTEP(ks) { \
    bf16x8 ef = *(const bf16x8*)&ET[((size_t)((ks) * 4 + lg4) * N_EMB + eb + r15) * 8]; \
    bf16x8 x0 = *(const bf16x8*)&XL[(((ks) * 4 + lg4) * 64 + 0 * 16 + r15) * 8]; \
    bf16x8 x1 = *(const bf16x8*)&XL[(((ks) * 4 + lg4) * 64 + 1 * 16 + r15) * 8]; \
    bf16x8 x2 = *(const bf16x8*)&XL[(((ks) * 4 + lg4) * 64 + 2 * 16 + r15) * 8]; \
    bf16x8 x3 = *(const bf16x8*)&XL[(((ks) * 4 + lg4) * 64 + 3 * 16 + r15) * 8]; \
    a_0 = __builtin_amdgcn_mfma_f32_16x16x32_bf16(ef, x0, a_0, 0, 0, 0); \
    a_1 = __builtin_amdgcn_mfma_f32_16x16x32_bf16(ef, x1, a_1, 0, 0, 0); \
    a_2 = __builtin_amdgcn_mfma_f32_16x16x32_bf16(ef, x2, a_2, 0, 0, 0); \
    a_3 = __builtin_amdgcn_mfma_f32_16x16x32_bf16(ef, x3, a_3, 0, 0, 0); }
    KSTEP(0) KSTEP(1) KSTEP(2) KSTEP(3) KSTEP(4) KSTEP(5) KSTEP(6) KSTEP(7)
#define INSJ(j) { \
    int er = eb + lg4 * 4 + (j); \
    float en = enorm[er]; \
    ins3(en - 2.0f * a_0[j], er, tv0_0, ti0_0, tv1_0, ti1_0, tv2_0, ti2_0); \
    ins3(en - 2.0f * a_1[j], er, tv0_1, ti0_1, tv1_1, ti1_1, tv2_1, ti2_1); \
    ins3(en - 2.0f * a_2[j], er, tv0_2, ti0_2, tv1_2, ti1_2, tv2_2, ti2_2); \
    ins3(en - 2.0f * a_3[j], er, tv0_3, ti0_3, tv1_3, ti1_3, tv2_3, ti2_3); }
    INSJ(0) INSJ(1) INSJ(2) INSJ(3)
  }
  // merge the 4 lg4 groups (disjoint E subsets, same X-row per r15): xor 16 then 32
#define MERGESTORE(xs) { \
    mrg3(16, tv0_##xs, ti0_##xs, tv1_##xs, ti1_##xs, tv2_##xs, ti2_##xs); \
    mrg3(32, tv0_##xs, ti0_##xs, tv1_##xs, ti1_##xs, tv2_##xs, ti2_##xs); \
    if (lane < 16){ \
      int row = xbase + (xs) * 16 + lane; \
      size_t base = ((size_t)row * 8 + h * 4 + w) * 3; \
      partial[base + 0] = (f32x2){tv0_##xs, __int_as_float(ti0_##xs)}; \
      partial[base + 1] = (f32x2){tv1_##xs, __int_as_float(ti1_##xs)}; \
      partial[base + 2] = (f32x2){tv2_##xs, __int_as_float(ti2_##xs)}; } }
  MERGESTORE(0) MERGESTORE(1) MERGESTORE(2) MERGESTORE(3)
}

// ---------------- merge partials -> top3 + quantize + loss partials (R13-proven) ----------------
__global__ __launch_bounds__(256) void k_mq(
    const f32x2* __restrict__ partial, const float* __restrict__ X, const float* __restrict__ E,
    float* out, int* __restrict__ counts, float* __restrict__ partials)
{
  int wid = threadIdx.x >> 6, lane = threadIdx.x & 63;
  int row = blockIdx.x * 4 + wid;
  const f32x2* pr = partial + (size_t)row * 24;   // 8 E-slices x 3 sorted triples
  float v0 = __builtin_inff(), v1 = __builtin_inff(), v2 = __builtin_inff();
  int   i0 = 0x7fffffff,       i1 = 0x7fffffff,       i2 = 0x7fffffff;
  if (lane < 24){ f32x2 p = pr[lane]; ins3(p[0], __float_as_int(p[1]), v0, i0, v1, i1, v2, i2); }
  #pragma unroll
  for (int off = 1; off < 64; off <<= 1)
    mrg3(off, v0, i0, v1, i1, v2, i2);
  // butterfly all-reduce: every lane now holds the global sorted triple
  if (lane == 0){
    out[OFF_IDX + (size_t)row * 3 + 0] = (float)i0;
    out[OFF_IDX + (size_t)row * 3 + 1] = (float)i1;
    out[OFF_IDX + (size_t)row * 3 + 2] = (float)i2;
    atomicAdd(&counts[i0], 1); atomicAdd(&counts[i1], 1); atomicAdd(&counts[i2], 1);
  }
  // quantize + straight-through + loss partial (literal STE: x + (e - x))
  int c4 = lane * 4;
  f32x4 x4 = *(const f32x4*)&X[(size_t)row * C_DIM + c4];
  int idx[3] = {i0, i1, i2};
  float lsum = 0.f;
  #pragma unroll
  for (int t = 0; t < 3; t++){
    f32x4 e4 = *(const f32x4*)&E[(size_t)idx[t] * C_DIM + c4];
    #pragma unroll
    for (int q = 0; q < 4; q++){
      float diff = e4[q] - x4[q];
      out[OFF_Q + ((size_t)row * 3 + t) * C_DIM + c4 + q] = x4[q] + diff;
      lsum += diff * diff;
    }
  }
  #pragma unroll
  for (int off = 32; off > 0; off >>= 1) lsum += __shfl_down(lsum, off);
  if (lane == 0) partials[row] = lsum;
}

// ---------------- scalars: loss + perplexity ----------------
__global__ __launch_bounds__(256) void k_final(
    const float* __restrict__ partials, const int* __restrict__ counts,
    float* __restrict__ out)
{
  int t = threadIdx.x;
  float ls = 0.f;
  for (int i = t; i < N_ROWS; i += 256) ls += partials[i];
  float es = 0.f;
  for (int i = t; i < N_EMB; i += 256){
    float p = (float)counts[i] * (1.0f / 16384.0f);
    es += p * logf(p + 1e-10f);
  }
  __shared__ float r1[256], r2[256];
  r1[t] = ls; r2[t] = es; __syncthreads();
  for (int s = 128; s > 0; s >>= 1){
    if (t < s){ r1[t] += r1[t + s]; r2[t] += r2[t + s]; }
    __syncthreads();
  }
  if (t == 0){
    out[OFF_LOSS] = 0.25f * r1[0] / 12582912.0f;
    out[OFF_PERP] = expf(-r2[0]);
  }
}

extern "C" void kernel_launch(void* const* d_in, const int* in_sizes, int n_in,
                              void* d_out, int out_size, void* d_ws, size_t ws_size,
                              hipStream_t stream)
{
  const float* X = (const float*)d_in[0];
  const float* E = (const float*)d_in[1];
  float* out = (float*)d_out;
  char* ws = (char*)d_ws;
  // ws layout (bytes), total ~16 MB
  short* XT       = (short*)(ws + 0);          // 8388608   (K-chunk-major bf16)
  short* ET       = (short*)(ws + 8388608);    // 4194304   (K-chunk-major bf16)
  float* xnorm    = (float*)(ws + 12582912);   // 65536
  float* enorm    = (float*)(ws + 12648448);   // 32768
  f32x2* partial  = (f32x2*)(ws + 12681216);   // 16384*8*3*8 = 3145728
  int*   counts   = (int*)  (ws + 15826944);   // 32768
  float* partials = (float*)(ws + 15859712);   // 65536

  hipMemsetAsync(counts, 0, N_EMB * sizeof(int), stream);
  k_prep<<<(N_ROWS + N_EMB) / 8, 256, 0, stream>>>(X, E, XT, ET, xnorm, enorm);
  k_gemm<<<2048, 512, 0, stream>>>(XT, ET, xnorm, enorm, out);
  k_t3<<<512, 256, 0, stream>>>(XT, ET, enorm, partial);
  k_mq<<<N_ROWS / 4, 256, 0, stream>>>(partial, X, E, out, counts, partials);
  k_final<<<1, 256, 0, stream>>>(partials, counts, out);
}

// Round 18
// 346.231 us; speedup vs baseline: 2.2882x; 2.2249x over previous
//
#include <hip/hip_runtime.h>
#include <stdint.h>

// Problem constants
#define N_ROWS 16384   // 16*1024 flattened input rows
#define N_EMB  8192    // codebook size
#define C_DIM  256     // embedding dim
#define NKT    8       // pure-bf16 GEMM: K=256, 8 K-tiles of 32 (R9-validated)

// d_out layout (float element offsets), outputs concatenated in return order:
// loss(1), quantized_st(16*1024*3*256), perplexity(1), encoding_indices(16384*3), distances(16384*8192)
#define OFF_LOSS 0ull
#define OFF_Q    1ull
#define OFF_PERP 12582913ull
#define OFF_IDX  12582914ull
#define OFF_DIST 12632066ull

typedef short bf16x8 __attribute__((ext_vector_type(8)));
typedef float f32x4  __attribute__((ext_vector_type(4)));
typedef float f32x2  __attribute__((ext_vector_type(2)));

// ---------------- prep: fp32 -> bf16 (rne), K-chunk-major layout + fp32 row norms ----------------
// Layout: element (row, k) lives at dst[ ((k>>3)*NR + row)*8 + (k&7) ]
// i.e. [k_chunk][row][8 bf16]: GEMM staging is linear/coalesced AND LDS reads conflict-free.
__device__ __forceinline__ unsigned short f2bf_rne(float f){
  unsigned u = __float_as_uint(f);
  unsigned r = 0x7fffu + ((u >> 16) & 1u);
  return (unsigned short)((u + r) >> 16);
}

__global__ __launch_bounds__(256) void k_prep(
    const float* __restrict__ X, const float* __restrict__ E,
    short* __restrict__ XT, short* __restrict__ ET,
    float* __restrict__ xnorm, float* __restrict__ enorm)
{
  int b = blockIdx.x; int tid = threadIdx.x;
  const float* src; short* dst; float* nrm; int r0, NR;
  if (b < N_ROWS / 8){ r0 = b * 8;                src = X; dst = XT; nrm = xnorm; NR = N_ROWS; }
  else               { r0 = (b - N_ROWS / 8) * 8; src = E; dst = ET; nrm = enorm; NR = N_EMB;  }
  int e = tid & 7, rsub = (tid >> 3) & 7, qg = tid >> 6;   // 8e x 8row x 4qg
  int row = r0 + rsub;
  float s = 0.f;
  #pragma unroll
  for (int qq = 0; qq < 8; qq++){
    int q = qg * 8 + qq;                 // k-chunk [0,32) covering K=256
    float x = src[(size_t)row * C_DIM + q * 8 + e];
    dst[((size_t)q * NR + row) * 8 + e] = (short)f2bf_rne(x);
    s += x * x;
  }
  __shared__ float red[8][33];
  red[rsub][qg * 8 + e] = s;
  __syncthreads();
  if (tid < 8){
    float t = 0.f;
    #pragma unroll
    for (int i = 0; i < 32; i++) t += red[tid][i];
    nrm[r0 + tid] = t;
  }
}

// ---------------- GEMM: BM=256 BN=256 BK=32, 8 waves (2M x 4N of 128x64 wave-tiles) ----------------
// R9-exact. LDS 64 KB (dbuf 2 x 32 KB); launch_bounds(512,2): VGPR=128 no spill -> 2 blocks/CU.
// Counted-vmcnt pipeline, raw barriers, plain-store epilogue. Fused top-k REJECTED (R4: shfl storm,
// R10: I-cache/barrier pathology); recompute top-k REJECTED (R13-R17: 5x ~550us, structure-bound).
__device__ __forceinline__ void gload16(void* lds, const void* g){
  __builtin_amdgcn_global_load_lds(
      (const __attribute__((address_space(1))) void*)g,
      (__attribute__((address_space(3))) void*)lds, 16, 0, 0);
}

__global__ __launch_bounds__(512, 2) void k_gemm(
    const short* __restrict__ XT, const short* __restrict__ ET,
    const float* __restrict__ xnorm, const float* __restrict__ enorm,
    float* __restrict__ out)
{
  // LDS: [buf][q=0..3][row 0..255][8 bf16]; 16 KB per matrix per buffer = 64 KB total
  __shared__ __align__(16) short As[2][4 * 256 * 8];
  __shared__ __align__(16) short Bs[2][4 * 256 * 8];
  int tid = threadIdx.x;
  int lane = tid & 63, w = tid >> 6;
  int wr = w >> 2, wc = w & 3;          // wave grid 2M x 4N; wave-tile 128 x 64
  // R4/R6-measured swizzle: XCD x owns bn in [4x,4x+4); B slice 512 KB -> L2-resident.
  int id = blockIdx.x;                  // 2048 blocks = 64 bm x 32 bn
  int x = id & 7, jj = id >> 3, c = jj >> 5, u = jj & 31;
  int bm = c * 8 + (u >> 2);            // [0,64)
  int bn = x * 4 + (u & 3);             // [0,32)

  f32x4 acc[8][4];
  #pragma unroll
  for (int m = 0; m < 8; m++)
    #pragma unroll
    for (int n = 0; n < 4; n++) acc[m][n] = (f32x4){0.f, 0.f, 0.f, 0.f};

  // staging one K-tile (K=32) = 32 wave-gloads (A: 4q x 4 quarters, B: same); wave w takes 4
  auto stage = [&](int buf, int kt){
    #pragma unroll
    for (int i = 0; i < 4; i++){
      int p = w * 4 + i;                // wave-uniform
      if (p < 16){
        int q = p >> 2, qr = p & 3;
        gload16(&As[buf][(q * 256 + qr * 64) * 8],
                XT + ((size_t)(kt * 4 + q) * N_ROWS + (size_t)bm * 256 + qr * 64 + lane) * 8);
      } else {
        int pb = p - 16; int q = pb >> 2, qr = pb & 3;
        gload16(&Bs[buf][(q * 256 + qr * 64) * 8],
                ET + ((size_t)(kt * 4 + q) * N_EMB + (size_t)bn * 256 + qr * 64 + lane) * 8);
      }
    }
  };

  int r15 = lane & 15, lg4 = lane >> 4;

  stage(0, 0); stage(1, 1);             // 8 loads/wave in flight

  #pragma unroll
  for (int t = 0; t < NKT; ++t){
    const int buf = t & 1;
    // tile t ready: only tile t+1's 4 loads may remain in flight.
    if (t < NKT - 1) { asm volatile("s_waitcnt vmcnt(4)" ::: "memory"); }
    else             { asm volatile("s_waitcnt vmcnt(0)" ::: "memory"); }
    __builtin_amdgcn_s_barrier();       // barrier 1: tile t fully in LDS

    bf16x8 af[8], bf[4];
    {
      int q = lg4;                      // q in [0,4): K = q*8 .. q*8+7 within this 32-K tile
      #pragma unroll
      for (int m = 0; m < 8; m++)
        af[m] = *(const bf16x8*)&As[buf][(q * 256 + wr * 128 + m * 16 + r15) * 8];
      #pragma unroll
      for (int n = 0; n < 4; n++)
        bf[n] = *(const bf16x8*)&Bs[buf][(q * 256 + wc * 64 + n * 16 + r15) * 8];
    }
    // MFMA cluster 0 (m 0..3)
    __builtin_amdgcn_s_setprio(1);
    #pragma unroll
    for (int m = 0; m < 4; m++)
      #pragma unroll
      for (int n = 0; n < 4; n++)
        acc[m][n] = __builtin_amdgcn_mfma_f32_16x16x32_bf16(af[m], bf[n], acc[m][n], 0, 0, 0);
    __builtin_amdgcn_s_setprio(0);

    asm volatile("s_waitcnt lgkmcnt(0)" ::: "memory"); // all my ds_reads of buf done
    __builtin_amdgcn_sched_barrier(0);
    __builtin_amdgcn_s_barrier();       // barrier 2: all waves done reading buf
    if (t < NKT - 2) stage(buf, t + 2); // restage into dead buffer

    // MFMA cluster 1 (m 4..7) — hides the stage issue
    __builtin_amdgcn_s_setprio(1);
    #pragma unroll
    for (int m = 4; m < 8; m++)
      #pragma unroll
      for (int n = 0; n < 4; n++)
        acc[m][n] = __builtin_amdgcn_mfma_f32_16x16x32_bf16(af[m], bf[n], acc[m][n], 0, 0, 0);
    __builtin_amdgcn_s_setprio(0);
  }

  // epilogue: dist = ||x||^2 + ||e||^2 - 2*dot  (C/D map: col=lane&15, row=(lane>>4)*4+j)
  // Plain per-lane stores; adjacent n-iterations complete each 128 B line in L2 (clean 537 MB).
  int lc = lane & 15;
  #pragma unroll
  for (int m = 0; m < 8; m++){
    int rb = bm * 256 + wr * 128 + m * 16 + lg4 * 4;
    float xn0 = xnorm[rb], xn1 = xnorm[rb+1], xn2 = xnorm[rb+2], xn3 = xnorm[rb+3];
    #pragma unroll
    for (int n = 0; n < 4; n++){
      int col = bn * 256 + wc * 64 + n * 16 + lc;
      float en = enorm[col];
      out[OFF_DIST + (size_t)(rb + 0) * N_EMB + col] = xn0 + en - 2.0f * acc[m][n][0];
      out[OFF_DIST + (size_t)(rb + 1) * N_EMB + col] = xn1 + en - 2.0f * acc[m][n][1];
      out[OFF_DIST + (size_t)(rb + 2) * N_EMB + col] = xn2 + en - 2.0f * acc[m][n][2];
      out[OFF_DIST + (size_t)(rb + 3) * N_EMB + col] = xn3 + en - 2.0f * acc[m][n][3];
    }
  }
}

// ---------------- top-3 per row + quantize + loss partial (fused; tie-break = jax.lax.top_k) ----------------
#define LT(av,ai,bv,bi) (((av) < (bv)) || ((av) == (bv) && (ai) < (bi)))

__global__ __launch_bounds__(256) void k_tq(
    const float* __restrict__ X, const float* __restrict__ E,
    float* out, int* __restrict__ counts, float* __restrict__ partials)
{
  int row = blockIdx.x; int tid = threadIdx.x;
  const f32x4* drow = (const f32x4*)(out + OFF_DIST + (size_t)row * N_EMB);
  float v0 = __builtin_inff(), v1 = __builtin_inff(), v2 = __builtin_inff();
  int   i0 = 0x7fffffff,       i1 = 0x7fffffff,       i2 = 0x7fffffff;
  for (int i = tid; i < N_EMB / 4; i += 256){
    f32x4 dv = __builtin_nontemporal_load(&drow[i]);
    #pragma unroll
    for (int j = 0; j < 4; j++){
      float d = dv[j]; int ii = i * 4 + j;
      if (LT(d, ii, v2, i2)){
        if (LT(d, ii, v1, i1)){
          v2 = v1; i2 = i1;
          if (LT(d, ii, v0, i0)){ v1 = v0; i1 = i0; v0 = d; i0 = ii; }
          else                  { v1 = d;  i1 = ii; }
        } else { v2 = d; i2 = ii; }
      }
    }
  }
  // wave butterfly merge of sorted triples
  #pragma unroll
  for (int off = 1; off < 64; off <<= 1){
    float b0 = __shfl_xor(v0, off), b1 = __shfl_xor(v1, off), b2 = __shfl_xor(v2, off);
    int   j0 = __shfl_xor(i0, off), j1 = __shfl_xor(i1, off), j2 = __shfl_xor(i2, off);
    float a0 = v0, a1 = v1, a2 = v2; int x0 = i0, x1 = i1, x2 = i2;
    float r0, r1, r2; int s0, s1, s2;
    if (LT(a0, x0, b0, j0)){ r0 = a0; s0 = x0; a0 = a1; x0 = x1; a1 = a2; x1 = x2; a2 = __builtin_inff(); x2 = 0x7fffffff; }
    else                   { r0 = b0; s0 = j0; b0 = b1; j0 = j1; b1 = b2; j1 = j2; b2 = __builtin_inff(); j2 = 0x7fffffff; }
    if (LT(a0, x0, b0, j0)){ r1 = a0; s1 = x0; a0 = a1; x0 = x1; a1 = a2; x1 = x2; a2 = __builtin_inff(); x2 = 0x7fffffff; }
    else                   { r1 = b0; s1 = j0; b0 = b1; j0 = j1; b1 = b2; j1 = j2; b2 = __builtin_inff(); j2 = 0x7fffffff; }
    if (LT(a0, x0, b0, j0)){ r2 = a0; s2 = x0; }
    else                   { r2 = b0; s2 = j0; }
    v0 = r0; i0 = s0; v1 = r1; i1 = s1; v2 = r2; i2 = s2;
  }
  __shared__ float swv[4][3]; __shared__ int swi[4][3];
  int lane = tid & 63, wid = tid >> 6;
  if (lane == 0){
    swv[wid][0] = v0; swv[wid][1] = v1; swv[wid][2] = v2;
    swi[wid][0] = i0; swi[wid][1] = i1; swi[wid][2] = i2;
  }
  __syncthreads();
  if (tid == 0){
    for (int wq = 1; wq < 4; wq++){
      for (int t = 0; t < 3; t++){
        float d = swv[wq][t]; int i = swi[wq][t];
        if (LT(d, i, v2, i2)){
          if (LT(d, i, v1, i1)){
            v2 = v1; i2 = i1;
            if (LT(d, i, v0, i0)){ v1 = v0; i1 = i0; v0 = d; i0 = i; }
            else                 { v1 = d;  i1 = i; }
          } else { v2 = d; i2 = i; }
        }
      }
    }
    out[OFF_IDX + (size_t)row * 3 + 0] = (float)i0;
    out[OFF_IDX + (size_t)row * 3 + 1] = (float)i1;
    out[OFF_IDX + (size_t)row * 3 + 2] = (float)i2;
    swi[0][0] = i0; swi[0][1] = i1; swi[0][2] = i2;   // broadcast final triple
    atomicAdd(&counts[i0], 1); atomicAdd(&counts[i1], 1); atomicAdd(&counts[i2], 1);
  }
  __syncthreads();
  // quantize + straight-through + loss partial (literal STE: x + (e - x)); c = tid
  int fi0 = swi[0][0], fi1 = swi[0][1], fi2 = swi[0][2];
  float xv = X[(size_t)row * C_DIM + tid];
  float lsum = 0.f;
  {
    float e = E[(size_t)fi0 * C_DIM + tid]; float d = e - xv;
    out[OFF_Q + ((size_t)row * 3 + 0) * C_DIM + tid] = xv + d; lsum += d * d;
  }
  {
    float e = E[(size_t)fi1 * C_DIM + tid]; float d = e - xv;
    out[OFF_Q + ((size_t)row * 3 + 1) * C_DIM + tid] = xv + d; lsum += d * d;
  }
  {
    float e = E[(size_t)fi2 * C_DIM + tid]; float d = e - xv;
    out[OFF_Q + ((size_t)row * 3 + 2) * C_DIM + tid] = xv + d; lsum += d * d;
  }
  __shared__ float qred[256];
  qred[tid] = lsum; __syncthreads();
  for (int s = 128; s > 0; s >>= 1){ if (tid < s) qred[tid] += qred[tid + s]; __syncthreads(); }
  if (tid == 0) partials[row] = qred[0];
}

// ---------------- scalars: loss + perplexity ----------------
__global__ __launch_bounds__(256) void k_final(
    const float* __restrict__ partials, const int* __restrict__ counts,
    float* __restrict__ out)
{
  int t = threadIdx.x;
  float ls = 0.f;
  for (int i = t; i < N_ROWS; i += 256) ls += partials[i];
  float es = 0.f;
  for (int i = t; i < N_EMB; i += 256){
    float p = (float)counts[i] * (1.0f / 16384.0f);
    es += p * logf(p + 1e-10f);
  }
  __shared__ float r1[256], r2[256];
  r1[t] = ls; r2[t] = es; __syncthreads();
  for (int s = 128; s > 0; s >>= 1){
    if (t < s){ r1[t] += r1[t + s]; r2[t] += r2[t + s]; }
    __syncthreads();
  }
  if (t == 0){
    out[OFF_LOSS] = 0.25f * r1[0] / 12582912.0f;
    out[OFF_PERP] = expf(-r2[0]);
  }
}

extern "C" void kernel_launch(void* const* d_in, const int* in_sizes, int n_in,
                              void* d_out, int out_size, void* d_ws, size_t ws_size,
                              hipStream_t stream)
{
  const float* X = (const float*)d_in[0];
  const float* E = (const float*)d_in[1];
  float* out = (float*)d_out;
  char* ws = (char*)d_ws;
  // ws layout (bytes), total ~12.8 MB
  short* XT       = (short*)(ws + 0);          // 8388608   (K-chunk-major bf16)
  short* ET       = (short*)(ws + 8388608);    // 4194304   (K-chunk-major bf16)
  float* xnorm    = (float*)(ws + 12582912);   // 65536
  float* enorm    = (float*)(ws + 12648448);   // 32768
  int*   counts   = (int*)  (ws + 12681216);   // 32768
  float* partials = (float*)(ws + 12713984);   // 65536

  hipMemsetAsync(counts, 0, N_EMB * sizeof(int), stream);
  k_prep<<<(N_ROWS + N_EMB) / 8, 256, 0, stream>>>(X, E, XT, ET, xnorm, enorm);
  k_gemm<<<2048, 512, 0, stream>>>(XT, ET, xnorm, enorm, out);
  k_tq<<<N_ROWS, 256, 0, stream>>>(X, E, out, counts, partials);
  k_final<<<1, 256, 0, stream>>>(partials, counts, out);
}